// Round 6
// baseline (438.403 us; speedup 1.0000x reference)
//
#include <hip/hip_runtime.h>
#include <stdint.h>

typedef unsigned short u16;
typedef unsigned int u32;
typedef _Float16 f16;
typedef _Float16 f16x8 __attribute__((ext_vector_type(8)));
typedef _Float16 f16x4 __attribute__((ext_vector_type(4)));
typedef float f32x4 __attribute__((ext_vector_type(4)));
typedef float f32x16 __attribute__((ext_vector_type(16)));

#define B_ 32
#define C_ 256
#define S_ 1024

// ---------------------------------------------------------------------------
// Router MLP (g holds raw sums; scaled here)
// ---------------------------------------------------------------------------
__global__ __launch_bounds__(256) void k_mlp(
    const float* __restrict__ g,
    const float* __restrict__ w1, const float* __restrict__ b1,
    const float* __restrict__ w2, const float* __restrict__ b2,
    float* __restrict__ out)
{
    int b = blockIdx.x, tid = threadIdx.x;
    __shared__ float sg[512];
    __shared__ float sh[128];
    sg[tid]     = g[b*512 + tid]       * (1.0f/1024.0f);
    sg[tid+256] = g[b*512 + 256 + tid] * (1.0f/1024.0f);
    __syncthreads();
    if (tid < 128){
        float a = b1[tid];
        const float* w = w1 + (size_t)tid*512;
        #pragma unroll 4
        for (int k = 0; k < 512; k += 4){
            float4 wv = *(const float4*)(w + k);
            a += sg[k]*wv.x + sg[k+1]*wv.y + sg[k+2]*wv.z + sg[k+3]*wv.w;
        }
        sh[tid] = fmaxf(a, 0.f);
    }
    __syncthreads();
    if (tid < 4){
        float a = b2[tid];
        const float* w = w2 + (size_t)tid*128;
        for (int k = 0; k < 128; ++k) a += sh[k]*w[k];
        out[(size_t)8388608 + b*4 + tid] = 1.f/(1.f+expf(-a));
    }
}

// ---------------------------------------------------------------------------
// Weight convert fp32 -> f16
// ---------------------------------------------------------------------------
__global__ __launch_bounds__(256) void k_cvtw(
    const float* __restrict__ Wq, const float* __restrict__ Wk,
    const float* __restrict__ Wv, const float* __restrict__ cw,
    f16* __restrict__ Wqf, f16* __restrict__ Wkf,
    f16* __restrict__ Wvf, f16* __restrict__ cwf)
{
    int i = (blockIdx.x*256 + threadIdx.x) * 4;
    const float* src; f16* dst; int off;
    if (i < 65536){ src = Wq; dst = Wqf; off = i; }
    else if (i < 131072){ src = Wk; dst = Wkf; off = i - 65536; }
    else if (i < 196608){ src = Wv; dst = Wvf; off = i - 131072; }
    else { src = cw; dst = cwf; off = i - 196608; }
    float4 v = *(const float4*)(src + off);
    f16x4 r = { (f16)v.x, (f16)v.y, (f16)v.z, (f16)v.w };
    *(f16x4*)(dst + off) = r;
}

// ---------------------------------------------------------------------------
// Input convert+transpose fp32 [c][s] -> f16 [s][c] + fused pool (atomics)
// ---------------------------------------------------------------------------
__global__ __launch_bounds__(256) void k_cvt(
    const float* __restrict__ lidar, const float* __restrict__ hsi,
    f16* __restrict__ lidT, f16* __restrict__ hsiT,
    float* __restrict__ g)
{
    int z = blockIdx.z, which = z >> 5, b = z & 31;
    const float* src = (which ? hsi : lidar) + (size_t)b*C_*S_;
    f16* dst = (which ? hsiT : lidT) + (size_t)b*S_*C_;
    int tid = threadIdx.x;
    int c4 = blockIdx.y*64 + (tid&15)*4;
    int s4 = blockIdx.x*64 + (tid>>4)*4;
    float4 m[4];
    #pragma unroll
    for (int r = 0; r < 4; ++r) m[r] = *(const float4*)(src + (size_t)(c4+r)*S_ + s4);
    f16x4 t0 = { (f16)m[0].x, (f16)m[1].x, (f16)m[2].x, (f16)m[3].x };
    f16x4 t1 = { (f16)m[0].y, (f16)m[1].y, (f16)m[2].y, (f16)m[3].y };
    f16x4 t2 = { (f16)m[0].z, (f16)m[1].z, (f16)m[2].z, (f16)m[3].z };
    f16x4 t3 = { (f16)m[0].w, (f16)m[1].w, (f16)m[2].w, (f16)m[3].w };
    *(f16x4*)(dst + (size_t)(s4+0)*C_ + c4) = t0;
    *(f16x4*)(dst + (size_t)(s4+1)*C_ + c4) = t1;
    *(f16x4*)(dst + (size_t)(s4+2)*C_ + c4) = t2;
    *(f16x4*)(dst + (size_t)(s4+3)*C_ + c4) = t3;
    float ps[4];
    #pragma unroll
    for (int r = 0; r < 4; ++r){
        ps[r] = m[r].x + m[r].y + m[r].z + m[r].w;
        ps[r] += __shfl_xor(ps[r], 16, 64);
        ps[r] += __shfl_xor(ps[r], 32, 64);
    }
    __shared__ float sred[4][64];
    int wv = tid>>6, lane = tid&63;
    if ((lane>>4) == 0){
        #pragma unroll
        for (int r = 0; r < 4; ++r) sred[wv][(lane&15)*4 + r] = ps[r];
    }
    __syncthreads();
    if (tid < 64){
        float v = sred[0][tid] + sred[1][tid] + sred[2][tid] + sred[3][tid];
        atomicAdd(&g[b*512 + which*256 + blockIdx.y*64 + tid], v);
    }
}

// ---------------------------------------------------------------------------
// QKV projections, f16 MFMA, 128-s blocks (2 s-subblocks per wave, B-frag reuse)
// grid (8, 4, 192)
// ---------------------------------------------------------------------------
__global__ __launch_bounds__(256) void k_qkv(
    const f16* __restrict__ lidT, const f16* __restrict__ hsiT,
    const f16* __restrict__ Wqf, const f16* __restrict__ Wkf, const f16* __restrict__ Wvf,
    const float* __restrict__ bq, const float* __restrict__ bk, const float* __restrict__ bv,
    f16* __restrict__ Qf_l, f16* __restrict__ Kf_l,
    f16* __restrict__ Qf_h, f16* __restrict__ Kf_h,
    f16* __restrict__ Qt_l, f16* __restrict__ Qt_h,
    f16* __restrict__ Vt_l, f16* __restrict__ Vt_h)
{
    int z = blockIdx.z, combo = z >> 5, b = z & 31, ww = combo % 3;
    const f16* In = ((combo < 3) ? lidT : hsiT) + (size_t)b*S_*C_;
    const f16* Wf = (ww==0) ? Wqf : (ww==1) ? Wkf : Wvf;
    const float* bias = (ww==0) ? bq : (ww==1) ? bk : bv;
    int s0 = blockIdx.x*128, o0 = blockIdx.y*64;
    int tid = threadIdx.x, w = tid>>6, lane = tid&63, quad = lane>>4, l15 = lane&15;

    __shared__ __align__(16) f16 sA[128*72];   // In [s128][c64]  (also epilogue sT[64][136])
    __shared__ __align__(16) f16 sB[64*72];    // W  [o64][c64]

    f32x4 D[2][4];
    #pragma unroll
    for (int h = 0; h < 2; ++h)
        #pragma unroll
        for (int i = 0; i < 4; ++i) D[h][i] = (f32x4){0.f,0.f,0.f,0.f};

    int rowA = tid>>1, cA = (tid&1)*32;
    int rowB = tid>>2, cB = (tid&3)*16;
    for (int c0 = 0; c0 < 256; c0 += 64){
        __syncthreads();
        #pragma unroll
        for (int j = 0; j < 4; ++j)
            *(f16x8*)&sA[rowA*72 + cA + 8*j] = *(const f16x8*)(In + (size_t)(s0+rowA)*C_ + c0 + cA + 8*j);
        #pragma unroll
        for (int j = 0; j < 2; ++j)
            *(f16x8*)&sB[rowB*72 + cB + 8*j] = *(const f16x8*)(Wf + (size_t)(o0+rowB)*C_ + c0 + cB + 8*j);
        __syncthreads();
        #pragma unroll
        for (int sub = 0; sub < 2; ++sub){
            f16x8 a0 = *(const f16x8*)&sA[(w*16+l15)*72 + sub*32 + quad*8];
            f16x8 a1 = *(const f16x8*)&sA[((w+4)*16+l15)*72 + sub*32 + quad*8];
            #pragma unroll
            for (int bt = 0; bt < 4; ++bt){
                f16x8 bb = *(const f16x8*)&sB[(bt*16+l15)*72 + sub*32 + quad*8];
                D[0][bt] = __builtin_amdgcn_mfma_f32_16x16x32_f16(a0, bb, D[0][bt], 0,0,0);
                D[1][bt] = __builtin_amdgcn_mfma_f32_16x16x32_f16(a1, bb, D[1][bt], 0,0,0);
            }
        }
    }
    float bi[4];
    #pragma unroll
    for (int bt = 0; bt < 4; ++bt) bi[bt] = bias[o0 + bt*16 + l15];

    // s_loc(h) = h*64 + w*16 + quad*4 + r ; o_loc = bt*16 + l15
    if (ww != 2){
        f16* F = (ww==0) ? ((combo==0) ? Qf_l : Qf_h) : ((combo==1) ? Kf_l : Kf_h);
        F += (size_t)b*S_*C_;
        #pragma unroll
        for (int h = 0; h < 2; ++h)
            #pragma unroll
            for (int bt = 0; bt < 4; ++bt)
                #pragma unroll
                for (int r = 0; r < 4; ++r)
                    F[(size_t)(s0 + h*64 + w*16 + quad*4 + r)*C_ + o0 + bt*16 + l15] = (f16)(D[h][bt][r] + bi[bt]);
    }
    if (ww != 1){
        __syncthreads();
        // transpose: sT [o64][s128+8]
        #pragma unroll
        for (int h = 0; h < 2; ++h)
            #pragma unroll
            for (int bt = 0; bt < 4; ++bt)
                #pragma unroll
                for (int r = 0; r < 4; ++r)
                    sA[(bt*16+l15)*136 + h*64 + w*16 + quad*4 + r] = (f16)(D[h][bt][r] + bi[bt]);
        __syncthreads();
        f16* T = (combo==0) ? Qt_l : (combo==3) ? Qt_h : (combo==2) ? Vt_l : Vt_h;
        T += (size_t)b*C_*S_;
        int o_r = tid>>2, sc = (tid&3)*32;
        #pragma unroll
        for (int j = 0; j < 4; ++j)
            *(f16x8*)(T + (size_t)(o0+o_r)*S_ + s0 + sc + 8*j) = *(const f16x8*)&sA[o_r*136 + sc + 8*j];
    }
}

// ---------------------------------------------------------------------------
// QVT1[c][s] = Qt_l*Vt_h ; QVT2[c][s] = Qt_h*Vt_l
// ---------------------------------------------------------------------------
__global__ __launch_bounds__(256) void k_qv(
    const f16* __restrict__ Qt_l, const f16* __restrict__ Qt_h,
    const f16* __restrict__ Vt_l, const f16* __restrict__ Vt_h,
    f16* __restrict__ QVT1, f16* __restrict__ QVT2)
{
    size_t idx = (size_t)(blockIdx.x*256 + threadIdx.x) * 8;
    f16x8 a = *(const f16x8*)(Qt_l+idx);
    f16x8 b = *(const f16x8*)(Vt_h+idx);
    *(f16x8*)(QVT1+idx) = a*b;
    f16x8 c = *(const f16x8*)(Qt_h+idx);
    f16x8 d = *(const f16x8*)(Vt_l+idx);
    *(f16x8*)(QVT2+idx) = c*d;
}

// ---------------------------------------------------------------------------
// Flash attention v3: 32x32x16 MFMA, K direct from global, transposed scores.
// Block = 64 q-rows; waves: sh2=w&1 (s-half 32), hf=w>>1 (t-half for scores /
// c-half for PV).  t-tile 64, 16 iterations.
// Scores: St[t32][s32] = sum_c K[t][c] Q[s][c]  (A=K direct, B=Q regs)
// PV:     Dt[c32][s32] = sum_t QVT[c][t] P[s][t] (A=V from LDS, B=P from LDS)
// D-layout (verified): col = lane&31, row = (reg&3)+8*(reg>>2)+4*(lane>>5)
// ---------------------------------------------------------------------------
__global__ __launch_bounds__(256, 2) void k_attn(
    const f16* __restrict__ Qf_l, const f16* __restrict__ Kf_l,
    const f16* __restrict__ Qf_h, const f16* __restrict__ Kf_h,
    const f16* __restrict__ QVT1, const f16* __restrict__ QVT2,
    f16* __restrict__ cat)
{
    int inst = blockIdx.y;
    int b = inst >> 1, which = inst & 1;
    const f16* Qf  = (which ? Qf_h : Qf_l) + (size_t)b*S_*C_;
    const f16* Kf  = (which ? Kf_h : Kf_l) + (size_t)b*S_*C_;
    const f16* QVT = (which ? QVT2 : QVT1) + (size_t)b*C_*S_;
    f16* outp = cat + (size_t)b*S_*512 + (which ? 0 : 256);
    int s0 = blockIdx.x*64;
    int tid = threadIdx.x, w = tid>>6, lane = tid&63;
    int l31 = lane&31, b5 = lane>>5;
    int sh2 = w&1, hf = w>>1;

    __shared__ __align__(16) f16 sV[256*72];   // [c][t64]; epilogue reuse sE[64][264]
    __shared__ __align__(16) f16 sP[64*72];    // [s][t64]
    __shared__ float sRm[2][64], sRl[2][64];
    __shared__ float sSt[64][2];               // running m, l

    // Q B-frags (registers): B[n = s-local = l31][k = kap*16 + b5*8 + j]
    f16x8 qB[16];
    {
        const f16* qbase = Qf + (size_t)(s0 + 32*sh2 + l31)*C_ + b5*8;
        #pragma unroll
        for (int k = 0; k < 16; ++k) qB[k] = *(const f16x8*)(qbase + k*16);
    }
    if (tid < 64){ sSt[tid][0] = -1e30f; sSt[tid][1] = 0.f; }

    f32x16 pacc[4];
    #pragma unroll
    for (int i = 0; i < 4; ++i) pacc[i] = (f32x16)(0.f);

    const f16* kbase = Kf + (size_t)(32*hf + l31)*C_ + b5*8;
    int smy = 32*sh2 + l31;

    for (int tt = 0; tt < 16; ++tt){
        int t0 = tt*64;
        __syncthreads();
        // stage V tile [256 c][64 t]
        #pragma unroll
        for (int p = 0; p < 8; ++p){
            int idx = p*256 + tid; int row = idx>>3, t8 = (idx&7)*8;
            *(f16x8*)&sV[row*72 + t8] = *(const f16x8*)(QVT + (size_t)row*S_ + t0 + t8);
        }
        // K A-frags direct from global: A[m = t-local = l31][k]
        f16x8 kA[16];
        {
            const f16* kb = kbase + (size_t)t0*C_;
            #pragma unroll
            for (int k = 0; k < 16; ++k) kA[k] = *(const f16x8*)(kb + k*16);
        }
        __syncthreads();

        // scores St[t32][s32]
        f32x16 St = (f32x16)(0.f);
        #pragma unroll
        for (int k = 0; k < 16; ++k)
            St = __builtin_amdgcn_mfma_f32_32x32x16_f16(kA[k], qB[k], St, 0,0,0);

        // tile max over t (rows): in-lane 16 regs + partner half
        float tmax = St[0];
        #pragma unroll
        for (int i = 1; i < 16; ++i) tmax = fmaxf(tmax, St[i]);
        tmax = fmaxf(tmax, __shfl_xor(tmax, 32, 64));
        if (lane < 32) sRm[hf][32*sh2 + lane] = tmax;
        __syncthreads();

        float mo = sSt[smy][0];
        float mn = fmaxf(mo, fmaxf(sRm[0][smy], sRm[1][smy]));
        float p16[16];
        float ls = 0.f;
        #pragma unroll
        for (int i = 0; i < 16; ++i){ p16[i] = __expf(St[i] - mn); ls += p16[i]; }
        // write P[s][t] packed (rows t = 32*hf + 8g + 4*b5 + 0..3)
        #pragma unroll
        for (int g = 0; g < 4; ++g){
            f16x4 pk = { (f16)p16[4*g], (f16)p16[4*g+1], (f16)p16[4*g+2], (f16)p16[4*g+3] };
            *(f16x4*)&sP[smy*72 + 32*hf + 8*g + 4*b5] = pk;
        }
        ls += __shfl_xor(ls, 32, 64);
        if (lane < 32) sRl[hf][32*sh2 + lane] = ls;
        __syncthreads();

        float alpha = __expf(mo - mn);
        if (hf == 0 && lane < 32){
            float ln = sSt[smy][1]*alpha + sRl[0][smy] + sRl[1][smy];
            sSt[smy][0] = mn; sSt[smy][1] = ln;
        }
        #pragma unroll
        for (int ct = 0; ct < 4; ++ct)
            #pragma unroll
            for (int i = 0; i < 16; ++i) pacc[ct][i] *= alpha;

        // PV: Dt[c32][s32], A = V rows c, B = P rows s
        #pragma unroll
        for (int kp = 0; kp < 4; ++kp){
            f16x8 pB = *(const f16x8*)&sP[smy*72 + kp*16 + b5*8];
            #pragma unroll
            for (int ct = 0; ct < 4; ++ct){
                f16x8 vA = *(const f16x8*)&sV[(128*hf + 32*ct + l31)*72 + kp*16 + b5*8];
                pacc[ct] = __builtin_amdgcn_mfma_f32_32x32x16_f16(vA, pB, pacc[ct], 0,0,0);
            }
        }
    }

    // epilogue: transpose through LDS (sE[s64][c256+8] reuses sV) then coalesced store
    __syncthreads();
    float rl = 1.f / sSt[smy][1];
    f16* sE = sV;
    #pragma unroll
    for (int ct = 0; ct < 4; ++ct)
        #pragma unroll
        for (int i = 0; i < 16; ++i){
            int cl = 128*hf + 32*ct + (i&3) + 8*(i>>2) + 4*b5;
            sE[(32*sh2 + l31)*264 + cl] = (f16)(pacc[ct][i] * rl);
        }
    __syncthreads();
    {
        int s = tid>>2;
        #pragma unroll
        for (int i = 0; i < 8; ++i){
            int c8 = ((tid&3) + 4*i)*8;
            *(f16x8*)(outp + (size_t)(s0+s)*512 + c8) = *(const f16x8*)&sE[s*264 + c8];
        }
    }
}

// ---------------------------------------------------------------------------
// 1x1 conv + bias + residual, f16 MFMA, 128-o blocks (2 o-subblocks per wave)
// grid (16, 2, 32)
// ---------------------------------------------------------------------------
__global__ __launch_bounds__(256) void k_conv(
    const f16* __restrict__ cat, const f16* __restrict__ cwf,
    const float* __restrict__ cb, const float* __restrict__ x,
    float* __restrict__ out)
{
    int b = blockIdx.z;
    int s0 = blockIdx.x*64, o0 = blockIdx.y*128;
    int tid = threadIdx.x, w = tid>>6, lane = tid&63, quad = lane>>4, l15 = lane&15;

    __shared__ __align__(16) f16 sA[128*72];   // cw [o128][i64]
    __shared__ __align__(16) f16 sB[64*72];    // cat [s64][i64]

    f32x4 D[2][4];
    #pragma unroll
    for (int h = 0; h < 2; ++h)
        #pragma unroll
        for (int i = 0; i < 4; ++i) D[h][i] = (f32x4){0.f,0.f,0.f,0.f};

    const f16* catb = cat + (size_t)b*S_*512;
    int rowA = tid>>1, iA = (tid&1)*32;
    int rowB = tid>>2, iB = (tid&3)*16;
    for (int i0 = 0; i0 < 512; i0 += 64){
        __syncthreads();
        #pragma unroll
        for (int j = 0; j < 4; ++j)
            *(f16x8*)&sA[rowA*72 + iA + 8*j] = *(const f16x8*)(cwf + (size_t)(o0+rowA)*512 + i0 + iA + 8*j);
        #pragma unroll
        for (int j = 0; j < 2; ++j)
            *(f16x8*)&sB[rowB*72 + iB + 8*j] = *(const f16x8*)(catb + (size_t)(s0+rowB)*512 + i0 + iB + 8*j);
        __syncthreads();
        #pragma unroll
        for (int sub = 0; sub < 2; ++sub){
            f16x8 a0 = *(const f16x8*)&sA[(w*16+l15)*72 + sub*32 + quad*8];
            f16x8 a1 = *(const f16x8*)&sA[((w+4)*16+l15)*72 + sub*32 + quad*8];
            #pragma unroll
            for (int bt = 0; bt < 4; ++bt){
                f16x8 bb = *(const f16x8*)&sB[(bt*16+l15)*72 + sub*32 + quad*8];
                D[0][bt] = __builtin_amdgcn_mfma_f32_16x16x32_f16(a0, bb, D[0][bt], 0,0,0);
                D[1][bt] = __builtin_amdgcn_mfma_f32_16x16x32_f16(a1, bb, D[1][bt], 0,0,0);
            }
        }
    }
    #pragma unroll
    for (int h = 0; h < 2; ++h)
        #pragma unroll
        for (int r = 0; r < 4; ++r){
            int o_loc = h*64 + w*16 + quad*4 + r;
            float cbv = cb[o0 + o_loc];
            size_t base = (size_t)b*C_*S_ + (size_t)(o0+o_loc)*S_ + s0;
            #pragma unroll
            for (int bt = 0; bt < 4; ++bt){
                size_t a = base + bt*16 + l15;
                out[a] = D[h][bt][r] + cbv + x[a];
            }
        }
}

// ---------------------------------------------------------------------------
extern "C" void kernel_launch(void* const* d_in, const int* in_sizes, int n_in,
                              void* d_out, int out_size, void* d_ws, size_t ws_size,
                              hipStream_t stream)
{
    const float* lidar = (const float*)d_in[0];
    const float* hsi   = (const float*)d_in[1];
    const float* x     = (const float*)d_in[2];
    const float* Wq = (const float*)d_in[3];  const float* bq = (const float*)d_in[4];
    const float* Wk = (const float*)d_in[5];  const float* bk = (const float*)d_in[6];
    const float* Wv = (const float*)d_in[7];  const float* bv = (const float*)d_in[8];
    const float* cw = (const float*)d_in[9];  const float* cb = (const float*)d_in[10];
    const float* rw1 = (const float*)d_in[11]; const float* rb1 = (const float*)d_in[12];
    const float* rw2 = (const float*)d_in[13]; const float* rb2 = (const float*)d_in[14];
    float* outF = (float*)d_out;
    char* ws = (char*)d_ws;
    const size_t M = 1ull<<20;

    f16* lidT = (f16*)(ws +   0*M);   // alias: QVT1 after k_qkv
    f16* hsiT = (f16*)(ws +  16*M);   // alias: QVT2 after k_qkv
    f16* Qf_l = (f16*)(ws +  32*M);
    f16* Kf_l = (f16*)(ws +  48*M);
    f16* Qf_h = (f16*)(ws +  64*M);
    f16* Kf_h = (f16*)(ws +  80*M);
    f16* Qt_l = (f16*)(ws +  96*M);
    f16* Qt_h = (f16*)(ws + 112*M);
    f16* cat  = (f16*)(ws + 128*M);   // 32 MiB
    float* g  = (float*)(ws + 160*M); // 16 KB raw channel sums
    f16* Wqf  = (f16*)(ws + 161*M);
    f16* Wkf  = (f16*)(ws + 161*M + 131072);
    f16* Wvf  = (f16*)(ws + 161*M + 262144);
    f16* cwf  = (f16*)(ws + 161*M + 393216);
    f16* QVT1 = lidT;
    f16* QVT2 = hsiT;
    f16* Vt_l = (f16*)d_out;            // dead until k_conv; disjoint from path_prob
    f16* Vt_h = (f16*)d_out + 8388608;

    hipMemsetAsync(g, 0, 4096*sizeof(float), stream);
    k_cvtw<<<320, 256, 0, stream>>>(Wq, Wk, Wv, cw, Wqf, Wkf, Wvf, cwf);
    k_cvt<<<dim3(16,4,64), 256, 0, stream>>>(lidar, hsi, lidT, hsiT, g);
    k_mlp<<<32, 256, 0, stream>>>(g, rw1, rb1, rw2, rb2, outF);
    k_qkv<<<dim3(8,4,192), 256, 0, stream>>>(lidT, hsiT, Wqf, Wkf, Wvf, bq, bk, bv,
                                             Qf_l, Kf_l, Qf_h, Kf_h, Qt_l, Qt_h, Vt_l, Vt_h);
    k_qv<<<4096, 256, 0, stream>>>(Qt_l, Qt_h, Vt_l, Vt_h, QVT1, QVT2);
    k_attn<<<dim3(16,64), 256, 0, stream>>>(Qf_l, Kf_l, Qf_h, Kf_h, QVT1, QVT2, cat);
    k_conv<<<dim3(16,2,32), 256, 0, stream>>>(cat, cwf, cb, x, outF);
}